// Round 1
// baseline (1353.167 us; speedup 1.0000x reference)
//
#include <hip/hip_runtime.h>
#include <math.h>

#define TPB 256

// ---------------------------------------------------------------------------
// Generic tiled GEMM: C = A[M,K] @ W[N,K]^T, fp32, 64x64 tile, 4x4 per thread.
// Output remap: C[m*ldc + (n>>6)*gstride + (n&63) + coff]
//   gstride=64, coff=0  -> identity (plain row-major ldc)
//   gstride=128         -> scatter 64-groups into 128-wide head slots
// ---------------------------------------------------------------------------
__global__ __launch_bounds__(TPB) void gemm_bt(
    const float* __restrict__ A, const float* __restrict__ W, float* __restrict__ C,
    int M, int N, int K, int ldc, int gstride, int coff)
{
  __shared__ float As[16][68];
  __shared__ float Ws[16][68];
  const int bm = blockIdx.y * 64;
  const int bn = blockIdx.x * 64;
  const int t = threadIdx.x;
  const int tx = t & 15, ty = t >> 4;
  float acc[4][4] = {{0.f, 0.f, 0.f, 0.f}, {0.f, 0.f, 0.f, 0.f},
                     {0.f, 0.f, 0.f, 0.f}, {0.f, 0.f, 0.f, 0.f}};
  for (int k0 = 0; k0 < K; k0 += 16) {
#pragma unroll
    for (int i = 0; i < 4; ++i) {
      int e = i * 256 + t;
      int r = e >> 4, kk = e & 15;
      As[kk][r] = A[(size_t)(bm + r) * K + (k0 + kk)];
      Ws[kk][r] = W[(size_t)(bn + r) * K + (k0 + kk)];
    }
    __syncthreads();
#pragma unroll
    for (int kk = 0; kk < 16; ++kk) {
      float4 a = *(const float4*)&As[kk][ty * 4];
      float4 w = *(const float4*)&Ws[kk][tx * 4];
      acc[0][0] += a.x * w.x; acc[0][1] += a.x * w.y; acc[0][2] += a.x * w.z; acc[0][3] += a.x * w.w;
      acc[1][0] += a.y * w.x; acc[1][1] += a.y * w.y; acc[1][2] += a.y * w.z; acc[1][3] += a.y * w.w;
      acc[2][0] += a.z * w.x; acc[2][1] += a.z * w.y; acc[2][2] += a.z * w.z; acc[2][3] += a.z * w.w;
      acc[3][0] += a.w * w.x; acc[3][1] += a.w * w.y; acc[3][2] += a.w * w.z; acc[3][3] += a.w * w.w;
    }
    __syncthreads();
  }
#pragma unroll
  for (int i = 0; i < 4; ++i) {
    int m = bm + ty * 4 + i;
#pragma unroll
    for (int j = 0; j < 4; ++j) {
      int n = bn + tx * 4 + j;
      if (m < M && n < N)
        C[(size_t)m * ldc + ((n >> 6) * gstride) + (n & 63) + coff] = acc[i][j];
    }
  }
}

// ---------------------------------------------------------------------------
// RMS over 64-element groups (one wave per group), optional RoPE.
// Group gi -> row s = gi/groups_per_row, slot hh = gi%groups_per_row
// element address: buf + s*rowstride + hh*gstride + off + lane
// ---------------------------------------------------------------------------
__global__ __launch_bounds__(TPB) void rmsrope64(
    float* __restrict__ buf, const float* __restrict__ g,
    const float* __restrict__ cosb, const float* __restrict__ sinb,
    int ngroups, int groups_per_row, int rowstride, int gstride, int off,
    int do_rms, int do_rope)
{
  int gi = blockIdx.x * (TPB / 64) + (threadIdx.x >> 6);
  int l = threadIdx.x & 63;
  if (gi >= ngroups) return;
  int s = gi / groups_per_row;
  int hh = gi - s * groups_per_row;
  float* p = buf + (size_t)s * rowstride + hh * gstride + off;
  float x = p[l];
  if (do_rms) {
    float ss = x * x;
#pragma unroll
    for (int msk = 1; msk < 64; msk <<= 1) ss += __shfl_xor(ss, msk);
    x = x * rsqrtf(ss * (1.0f / 64.0f) + 1e-6f) * g[l];
  }
  if (do_rope) {
    float partner = __shfl_xor(x, 32);
    float c = cosb[s * 64 + l];
    float sn = sinb[s * 64 + l];
    x = x * c + ((l < 32) ? -partner : partner) * sn;
  }
  p[l] = x;
}

// RMS over 512-wide rows (one wave per row)
__global__ __launch_bounds__(TPB) void rms512(
    float* __restrict__ buf, const float* __restrict__ g, int nrows)
{
  int row = blockIdx.x * (TPB / 64) + (threadIdx.x >> 6);
  int l = threadIdx.x & 63;
  if (row >= nrows) return;
  float* p = buf + (size_t)row * 512;
  float x[8];
  float ss = 0.f;
#pragma unroll
  for (int i = 0; i < 8; ++i) { x[i] = p[i * 64 + l]; ss += x[i] * x[i]; }
#pragma unroll
  for (int msk = 1; msk < 64; msk <<= 1) ss += __shfl_xor(ss, msk);
  float r = rsqrtf(ss * (1.0f / 512.0f) + 1e-6f);
#pragma unroll
  for (int i = 0; i < 8; ++i) p[i * 64 + l] = x[i] * r * g[i * 64 + l];
}

// ---------------------------------------------------------------------------
// Flash attention fp32, causal. One block per (head, q-tile of 64).
// BQ=64, BK=32, HD=128. 256 threads: (ty,tx)=16x16; thread computes
// scores s[4 qrows][2 kcols] then PV acc[4 qrows][8 dcols].
// q layout [S,NH,128] stride 2048; k,v layout [S,NKV,128] stride 512.
// ---------------------------------------------------------------------------
__global__ __launch_bounds__(TPB) void attn_fwd(
    const float* __restrict__ q, const float* __restrict__ k,
    const float* __restrict__ v, float* __restrict__ o)
{
  __shared__ float Qs[128][68];   // transposed: Qs[d][qr]
  __shared__ float Ks[128][36];   // transposed: Ks[d][kr]
  __shared__ float Vs[32][132];   // Vs[kr][d]
  __shared__ float Ps[64][36];    // Ps[qr][kr]
  const int h = blockIdx.x;
  const int qt = blockIdx.y;
  const int kvh = h >> 2;
  const int t = threadIdx.x;
  const int tx = t & 15, ty = t >> 4;
  const int q0 = qt * 64;
  const float scale = 0.08838834764831845f;  // 1/sqrt(128)

#pragma unroll
  for (int i = 0; i < 32; ++i) {
    int e = i * 256 + t;
    int qr = e >> 7, d = e & 127;
    Qs[d][qr] = q[(size_t)(q0 + qr) * 2048 + h * 128 + d];
  }
  float m_i[4], l_i[4], accv[4][8];
#pragma unroll
  for (int i = 0; i < 4; ++i) {
    m_i[i] = -1e30f; l_i[i] = 0.f;
#pragma unroll
    for (int j = 0; j < 8; ++j) accv[i][j] = 0.f;
  }
  const int nkt = (q0 + 64) >> 5;
  for (int kt = 0; kt < nkt; ++kt) {
    const int kbase = kt * 32;
    __syncthreads();  // protect Ks/Vs (prev iter) and Qs (first iter)
#pragma unroll
    for (int i = 0; i < 16; ++i) {
      int e = i * 256 + t;
      int kr = e >> 7, d = e & 127;
      size_t gidx = (size_t)(kbase + kr) * 512 + kvh * 128 + d;
      Ks[d][kr] = k[gidx];
      Vs[kr][d] = v[gidx];
    }
    __syncthreads();
    float s[4][2] = {{0.f, 0.f}, {0.f, 0.f}, {0.f, 0.f}, {0.f, 0.f}};
    for (int d = 0; d < 128; ++d) {
      float4 qv = *(const float4*)&Qs[d][ty * 4];
      float2 kv = *(const float2*)&Ks[d][tx * 2];
      s[0][0] += qv.x * kv.x; s[0][1] += qv.x * kv.y;
      s[1][0] += qv.y * kv.x; s[1][1] += qv.y * kv.y;
      s[2][0] += qv.z * kv.x; s[2][1] += qv.z * kv.y;
      s[3][0] += qv.w * kv.x; s[3][1] += qv.w * kv.y;
    }
    float corr[4];
#pragma unroll
    for (int i = 0; i < 4; ++i) {
      int qg = q0 + ty * 4 + i;
      float s0 = (kbase + tx * 2 + 0 <= qg) ? s[i][0] * scale : -1e30f;
      float s1 = (kbase + tx * 2 + 1 <= qg) ? s[i][1] * scale : -1e30f;
      float rm = fmaxf(s0, s1);
#pragma unroll
      for (int msk = 1; msk < 16; msk <<= 1) rm = fmaxf(rm, __shfl_xor(rm, msk));
      float mnew = fmaxf(m_i[i], rm);
      float c = __expf(m_i[i] - mnew);
      float p0 = __expf(s0 - mnew);
      float p1 = __expf(s1 - mnew);
      float rs = p0 + p1;
#pragma unroll
      for (int msk = 1; msk < 16; msk <<= 1) rs += __shfl_xor(rs, msk);
      l_i[i] = l_i[i] * c + rs;
      m_i[i] = mnew;
      corr[i] = c;
      Ps[ty * 4 + i][tx * 2 + 0] = p0;
      Ps[ty * 4 + i][tx * 2 + 1] = p1;
    }
    __syncthreads();  // Ps visible to all, Vs load complete
#pragma unroll
    for (int i = 0; i < 4; ++i)
#pragma unroll
      for (int j = 0; j < 8; ++j) accv[i][j] *= corr[i];
    for (int kk = 0; kk < 32; ++kk) {
      float4 v0 = *(const float4*)&Vs[kk][tx * 8];
      float4 v1 = *(const float4*)&Vs[kk][tx * 8 + 4];
#pragma unroll
      for (int i = 0; i < 4; ++i) {
        float p = Ps[ty * 4 + i][kk];
        accv[i][0] += p * v0.x; accv[i][1] += p * v0.y;
        accv[i][2] += p * v0.z; accv[i][3] += p * v0.w;
        accv[i][4] += p * v1.x; accv[i][5] += p * v1.y;
        accv[i][6] += p * v1.z; accv[i][7] += p * v1.w;
      }
    }
  }
#pragma unroll
  for (int i = 0; i < 4; ++i) {
    float inv = 1.0f / l_i[i];
#pragma unroll
    for (int j = 0; j < 8; ++j)
      o[(size_t)(q0 + ty * 4 + i) * 2048 + h * 128 + tx * 8 + j] = accv[i][j] * inv;
  }
}

// ---------------------------------------------------------------------------
extern "C" void kernel_launch(void* const* d_in, const int* in_sizes, int n_in,
                              void* d_out, int out_size, void* d_ws, size_t ws_size,
                              hipStream_t stream) {
  const float* x        = (const float*)d_in[0];
  const float* cosb     = (const float*)d_in[1];
  const float* sinb     = (const float*)d_in[2];
  const float* Wq_nope  = (const float*)d_in[3];
  const float* Wq_rope  = (const float*)d_in[4];
  const float* g_qnope  = (const float*)d_in[5];
  const float* g_qrope  = (const float*)d_in[6];
  const float* W_kv_down= (const float*)d_in[7];
  const float* g_ckv    = (const float*)d_in[8];
  const float* W_k_nope = (const float*)d_in[9];
  const float* W_k_rope = (const float*)d_in[10];
  const float* W_v      = (const float*)d_in[11];
  const float* W_o      = (const float*)d_in[12];
  float* out = (float*)d_out;

  const int S = 2048;
  float* ws   = (float*)d_ws;
  float* q    = ws;                    // S*16*128 = 4,194,304
  float* kbuf = q + 4194304;           // S*4*128  = 1,048,576
  float* vbuf = kbuf + 1048576;        // 1,048,576
  float* ckv  = vbuf + 1048576;        // S*512    = 1,048,576
  float* ao   = ckv + 1048576;         // 4,194,304

  dim3 blk(TPB);

  // x projections (K=2048)
  gemm_bt<<<dim3(16, 32), blk, 0, stream>>>(x, Wq_nope, q, S, 1024, 2048, 2048, 128, 0);
  gemm_bt<<<dim3(16, 32), blk, 0, stream>>>(x, Wq_rope, q, S, 1024, 2048, 2048, 128, 64);
  gemm_bt<<<dim3(8, 32),  blk, 0, stream>>>(x, W_kv_down, ckv, S, 512, 2048, 512, 64, 0);

  // norms + rope on q; rms on ckv
  rmsrope64<<<dim3((S * 16) / 4), blk, 0, stream>>>(q, g_qnope, nullptr, nullptr,
                                                    S * 16, 16, 2048, 128, 0, 1, 0);
  rmsrope64<<<dim3((S * 16) / 4), blk, 0, stream>>>(q, g_qrope, cosb, sinb,
                                                    S * 16, 16, 2048, 128, 64, 1, 1);
  rms512<<<dim3(S / 4), blk, 0, stream>>>(ckv, g_ckv, S);

  // kv projections (K=512)
  gemm_bt<<<dim3(4, 32), blk, 0, stream>>>(ckv, W_k_nope, kbuf, S, 256, 512, 512, 128, 0);
  gemm_bt<<<dim3(4, 32), blk, 0, stream>>>(ckv, W_k_rope, kbuf, S, 256, 512, 512, 128, 64);
  rmsrope64<<<dim3((S * 4) / 4), blk, 0, stream>>>(kbuf, nullptr, cosb, sinb,
                                                   S * 4, 4, 512, 128, 64, 0, 1);
  gemm_bt<<<dim3(8, 32), blk, 0, stream>>>(ckv, W_v, vbuf, S, 512, 512, 512, 64, 0);

  // attention
  attn_fwd<<<dim3(16, 32), blk, 0, stream>>>(q, kbuf, vbuf, ao);

  // output projection
  gemm_bt<<<dim3(32, 32), blk, 0, stream>>>(ao, W_o, out, S, 2048, 2048, 2048, 64, 0);
}

// Round 2
// 399.454 us; speedup vs baseline: 3.3875x; 3.3875x over previous
//
#include <hip/hip_runtime.h>
#include <hip/hip_bf16.h>
#include <math.h>

#define TPB 256

typedef __attribute__((ext_vector_type(8))) short bf16x8;
typedef __attribute__((ext_vector_type(4))) float f32x4;

__device__ __forceinline__ short f2bs(float x) {
  __hip_bfloat16 h = __float2bfloat16(x);
  return *reinterpret_cast<short*>(&h);
}

__device__ __forceinline__ void gll16(const void* g, void* l) {
  __builtin_amdgcn_global_load_lds(
      (const __attribute__((address_space(1))) unsigned int*)g,
      (__attribute__((address_space(3))) unsigned int*)l, 16, 0, 0);
}

// ---------------------------------------------------------------------------
// fp32 -> bf16 flat convert (n multiple of 4)
// ---------------------------------------------------------------------------
__global__ __launch_bounds__(TPB) void cvt_f2b(
    const float* __restrict__ s, __hip_bfloat16* __restrict__ d, int n)
{
  int i = (blockIdx.x * TPB + threadIdx.x) << 2;
  if (i >= n) return;
  const float4 v = *(const float4*)(s + i);
  short4 o;
  o.x = f2bs(v.x); o.y = f2bs(v.y); o.z = f2bs(v.z); o.w = f2bs(v.w);
  *(short4*)((short*)d + i) = o;
}

// ---------------------------------------------------------------------------
// vbuf fp32 [S][4*128] -> vt bf16 [4][128][S]  (64x64 LDS tile transpose)
// grid: (dt=2, st=32, kvh=4)
// ---------------------------------------------------------------------------
__global__ __launch_bounds__(TPB) void cvt_transpose_v(
    const float* __restrict__ v, __hip_bfloat16* __restrict__ vt)
{
  __shared__ float tile[64][65];
  const int dt = blockIdx.x, st = blockIdx.y, kvh = blockIdx.z;
  const int t = threadIdx.x;
  const int c = t & 63, r4 = t >> 6;
#pragma unroll
  for (int i = 0; i < 16; ++i) {
    int r = i * 4 + r4;
    tile[r][c] = v[(size_t)(st * 64 + r) * 512 + kvh * 128 + dt * 64 + c];
  }
  __syncthreads();
#pragma unroll
  for (int i = 0; i < 16; ++i) {
    int r = i * 4 + r4;
    vt[(size_t)kvh * 262144 + (size_t)(dt * 64 + r) * 2048 + st * 64 + c] =
        __float2bfloat16(tile[c][r]);
  }
}

// ---------------------------------------------------------------------------
// MFMA GEMM: C = A[M,K](bf16) @ W[N,K](bf16)^T -> fp32, 128x128 tile, BK=32,
// 4 waves (2x2 of 64x64), global_load_lds staging with XOR-swizzled LDS.
// mode 0: C[m*ldc+n]; mode 1: q nope/rope head scatter; mode 2: k/v scatter.
// M,N multiples of 128; K multiple of 32.
// ---------------------------------------------------------------------------
__global__ __launch_bounds__(TPB) void gemm_mfma(
    const __hip_bfloat16* __restrict__ A, const __hip_bfloat16* __restrict__ W,
    float* __restrict__ C, int M, int N, int K, int ldc, int mode)
{
  __shared__ short As[128 * 32];
  __shared__ short Bs[128 * 32];
  const int t = threadIdx.x;
  const int lane = t & 63, wave = t >> 6;
  const int wr = wave >> 1, wc = wave & 1;
  const int bm = blockIdx.y * 128, bn = blockIdx.x * 128;

  f32x4 acc[4][4];
#pragma unroll
  for (int m = 0; m < 4; ++m)
#pragma unroll
    for (int n = 0; n < 4; ++n) acc[m][n] = (f32x4){0.f, 0.f, 0.f, 0.f};

  const int r0 = t >> 2;               // staging row (0..63), +64 for 2nd
  const int kcl = (t & 3) ^ (r0 & 3);  // pre-swizzled logical k-chunk
  const int li = lane & 15, lh = lane >> 4;

  for (int k0 = 0; k0 < K; k0 += 32) {
    gll16(A + (size_t)(bm + r0) * K + k0 + (kcl << 3), &As[t * 8]);
    gll16(A + (size_t)(bm + r0 + 64) * K + k0 + (kcl << 3), &As[(t + 256) * 8]);
    gll16(W + (size_t)(bn + r0) * K + k0 + (kcl << 3), &Bs[t * 8]);
    gll16(W + (size_t)(bn + r0 + 64) * K + k0 + (kcl << 3), &Bs[(t + 256) * 8]);
    __syncthreads();
    bf16x8 af[4], bf[4];
#pragma unroll
    for (int m = 0; m < 4; ++m) {
      int r = wr * 64 + m * 16 + li;
      af[m] = *(const bf16x8*)&As[r * 32 + ((lh ^ (r & 3)) << 3)];
    }
#pragma unroll
    for (int n = 0; n < 4; ++n) {
      int r = wc * 64 + n * 16 + li;
      bf[n] = *(const bf16x8*)&Bs[r * 32 + ((lh ^ (r & 3)) << 3)];
    }
#pragma unroll
    for (int m = 0; m < 4; ++m)
#pragma unroll
      for (int n = 0; n < 4; ++n)
        acc[m][n] = __builtin_amdgcn_mfma_f32_16x16x32_bf16(af[m], bf[n], acc[m][n], 0, 0, 0);
    __syncthreads();
  }

#pragma unroll
  for (int m = 0; m < 4; ++m) {
    int gm = bm + wr * 64 + m * 16 + lh * 4;
#pragma unroll
    for (int n = 0; n < 4; ++n) {
      int gn = bn + wc * 64 + n * 16 + li;
#pragma unroll
      for (int j = 0; j < 4; ++j) {
        int mm = gm + j;
        size_t idx;
        if (mode == 0) {
          idx = (size_t)mm * ldc + gn;
        } else if (mode == 1) {  // q: n<1024 nope, >=1024 rope
          idx = (size_t)mm * 2048 + ((gn & 1023) >> 6) * 128 + ((gn >> 10) << 6) + (gn & 63);
        } else {                 // kv: 0-255 k_nope, 256-511 k_rope, 512+ v
          if (gn < 256)      idx = (size_t)mm * 512 + ((gn >> 6) << 7) + (gn & 63);
          else if (gn < 512) idx = (size_t)mm * 512 + (((gn - 256) >> 6) << 7) + 64 + (gn & 63);
          else               idx = 1048576u + (size_t)mm * 512 + (gn - 512);
        }
        C[idx] = acc[m][n][j];
      }
    }
  }
}

// ---------------------------------------------------------------------------
// RMS over 64-element groups (one wave per group), optional RoPE. (fp32)
// ---------------------------------------------------------------------------
__global__ __launch_bounds__(TPB) void rmsrope64(
    float* __restrict__ buf, const float* __restrict__ g,
    const float* __restrict__ cosb, const float* __restrict__ sinb,
    int ngroups, int groups_per_row, int rowstride, int gstride, int off,
    int do_rms, int do_rope)
{
  int gi = blockIdx.x * (TPB / 64) + (threadIdx.x >> 6);
  int l = threadIdx.x & 63;
  if (gi >= ngroups) return;
  int s = gi / groups_per_row;
  int hh = gi - s * groups_per_row;
  float* p = buf + (size_t)s * rowstride + hh * gstride + off;
  float x = p[l];
  if (do_rms) {
    float ss = x * x;
#pragma unroll
    for (int msk = 1; msk < 64; msk <<= 1) ss += __shfl_xor(ss, msk);
    x = x * rsqrtf(ss * (1.0f / 64.0f) + 1e-6f) * g[l];
  }
  if (do_rope) {
    float partner = __shfl_xor(x, 32);
    float c = cosb[s * 64 + l];
    float sn = sinb[s * 64 + l];
    x = x * c + ((l < 32) ? -partner : partner) * sn;
  }
  p[l] = x;
}

__global__ __launch_bounds__(TPB) void rms512(
    float* __restrict__ buf, const float* __restrict__ g, int nrows)
{
  int row = blockIdx.x * (TPB / 64) + (threadIdx.x >> 6);
  int l = threadIdx.x & 63;
  if (row >= nrows) return;
  float* p = buf + (size_t)row * 512;
  float x[8];
  float ss = 0.f;
#pragma unroll
  for (int i = 0; i < 8; ++i) { x[i] = p[i * 64 + l]; ss += x[i] * x[i]; }
#pragma unroll
  for (int msk = 1; msk < 64; msk <<= 1) ss += __shfl_xor(ss, msk);
  float r = rsqrtf(ss * (1.0f / 512.0f) + 1e-6f);
#pragma unroll
  for (int i = 0; i < 8; ++i) p[i * 64 + l] = x[i] * r * g[i * 64 + l];
}

// ---------------------------------------------------------------------------
// MFMA flash attention, causal. Block = 4 waves, BQ=64 (16 q-rows/wave),
// BK=64, HD=128. K,V staged via pre-swizzled global_load_lds; P via
// per-wave swizzled LDS. fp32 online softmax.
// qb [S][16*128], kb [S][4*128], vt [4][128][S], ob bf16 [S][16*128]
// ---------------------------------------------------------------------------
__global__ __launch_bounds__(TPB) void attn_mfma(
    const __hip_bfloat16* __restrict__ qb, const __hip_bfloat16* __restrict__ kb,
    const __hip_bfloat16* __restrict__ vt, __hip_bfloat16* __restrict__ ob)
{
  __shared__ short Ks[64 * 128];   // [kpos][d] swizzled
  __shared__ short Vs[128 * 64];   // [d][kpos] swizzled
  __shared__ short Ps[4][16 * 64]; // per-wave [q][kpos] swizzled
  const int h = blockIdx.x;
  const int qt = gridDim.y - 1 - blockIdx.y;  // longest blocks first
  const int kvh = h >> 2;
  const int t = threadIdx.x, lane = t & 63, wave = t >> 6;
  const int li = lane & 15, lh = lane >> 4;
  const int q0 = qt * 64, q0w = q0 + wave * 16;
  const float scale = 0.08838834764831845f;  // 1/sqrt(128)

  bf16x8 qf[4];
#pragma unroll
  for (int kd = 0; kd < 4; ++kd)
    qf[kd] = *(const bf16x8*)(qb + (size_t)(q0w + li) * 2048 + h * 128 + kd * 32 + lh * 8);

  f32x4 o[8];
#pragma unroll
  for (int n = 0; n < 8; ++n) o[n] = (f32x4){0.f, 0.f, 0.f, 0.f};
  float m_i[4] = {-1e30f, -1e30f, -1e30f, -1e30f};
  float l_i[4] = {0.f, 0.f, 0.f, 0.f};

  short* pw = Ps[wave];
  const int nkt = qt + 1;
  for (int kt = 0; kt < nkt; ++kt) {
    const int kbase = kt * 64;
    __syncthreads();  // prior tile's K/V reads complete
#pragma unroll
    for (int i = 0; i < 4; ++i) {  // K: 1024 16B-chunks
      int c = t + i * 256;
      int kpos = c >> 4, dcl = (c & 15) ^ (kpos & 7);
      gll16(kb + (size_t)(kbase + kpos) * 512 + kvh * 128 + dcl * 8, &Ks[c * 8]);
    }
#pragma unroll
    for (int i = 0; i < 4; ++i) {  // V: 1024 16B-chunks (transposed src)
      int c = t + i * 256;
      int d = c >> 3, kpl = (c & 7) ^ (d & 7);
      gll16(vt + (size_t)kvh * 262144 + (size_t)d * 2048 + kbase + kpl * 8, &Vs[c * 8]);
    }
    __syncthreads();  // staging drained

    // ---- S = Q K^T ----
    f32x4 s[4];
#pragma unroll
    for (int n = 0; n < 4; ++n) s[n] = (f32x4){0.f, 0.f, 0.f, 0.f};
#pragma unroll
    for (int n = 0; n < 4; ++n) {
      int kpos = n * 16 + li;
#pragma unroll
      for (int kd = 0; kd < 4; ++kd) {
        int cph = (kd * 4 + lh) ^ (kpos & 7);
        bf16x8 kf = *(const bf16x8*)&Ks[kpos * 128 + cph * 8];
        s[n] = __builtin_amdgcn_mfma_f32_16x16x32_bf16(qf[kd], kf, s[n], 0, 0, 0);
      }
    }
    // ---- scale + causal mask ----
    float sv[4][4];
    const bool diag = (kt == nkt - 1);
#pragma unroll
    for (int n = 0; n < 4; ++n)
#pragma unroll
      for (int j = 0; j < 4; ++j) {
        float val = s[n][j] * scale;
        if (diag) {
          int kg = kbase + n * 16 + li;
          int qg = q0w + lh * 4 + j;
          if (kg > qg) val = -1e30f;
        }
        sv[n][j] = val;
      }
    // ---- online softmax ----
    float c_[4];
#pragma unroll
    for (int j = 0; j < 4; ++j) {
      float rm = fmaxf(fmaxf(sv[0][j], sv[1][j]), fmaxf(sv[2][j], sv[3][j]));
      rm = fmaxf(rm, __shfl_xor(rm, 1));
      rm = fmaxf(rm, __shfl_xor(rm, 2));
      rm = fmaxf(rm, __shfl_xor(rm, 4));
      rm = fmaxf(rm, __shfl_xor(rm, 8));
      float mn = fmaxf(m_i[j], rm);
      c_[j] = __expf(m_i[j] - mn);
      m_i[j] = mn;
    }
#pragma unroll
    for (int n = 0; n < 4; ++n)
#pragma unroll
      for (int j = 0; j < 4; ++j) sv[n][j] = __expf(sv[n][j] - m_i[j]);
#pragma unroll
    for (int j = 0; j < 4; ++j) {
      float rs = sv[0][j] + sv[1][j] + sv[2][j] + sv[3][j];
      rs += __shfl_xor(rs, 1);
      rs += __shfl_xor(rs, 2);
      rs += __shfl_xor(rs, 4);
      rs += __shfl_xor(rs, 8);
      l_i[j] = l_i[j] * c_[j] + rs;
    }
    // ---- P -> LDS (bf16, swizzled) ----
#pragma unroll
    for (int n = 0; n < 4; ++n)
#pragma unroll
      for (int j = 0; j < 4; ++j) {
        int qq = lh * 4 + j, kp = n * 16 + li;
        pw[qq * 64 + (kp ^ ((qq & 7) << 3))] = f2bs(sv[n][j]);
      }
    // ---- rescale O ----
#pragma unroll
    for (int n = 0; n < 8; ++n)
#pragma unroll
      for (int j = 0; j < 4; ++j) o[n][j] *= c_[j];
    __syncthreads();  // P visible across wave lanes
    // ---- O += P V ----
#pragma unroll
    for (int kk = 0; kk < 2; ++kk) {
      int kp0 = kk * 32 + lh * 8;
      bf16x8 pf = *(const bf16x8*)&pw[li * 64 + (kp0 ^ ((li & 7) << 3))];
#pragma unroll
      for (int n = 0; n < 8; ++n) {
        int d = n * 16 + li;
        bf16x8 vf = *(const bf16x8*)&Vs[d * 64 + (kp0 ^ ((d & 7) << 3))];
        o[n] = __builtin_amdgcn_mfma_f32_16x16x32_bf16(pf, vf, o[n], 0, 0, 0);
      }
    }
  }
  float inv[4];
#pragma unroll
  for (int j = 0; j < 4; ++j) inv[j] = 1.0f / l_i[j];
#pragma unroll
  for (int n = 0; n < 8; ++n)
#pragma unroll
    for (int j = 0; j < 4; ++j)
      ob[(size_t)(q0w + lh * 4 + j) * 2048 + h * 128 + n * 16 + li] =
          __float2bfloat16(o[n][j] * inv[j]);
}

// ---------------------------------------------------------------------------
extern "C" void kernel_launch(void* const* d_in, const int* in_sizes, int n_in,
                              void* d_out, int out_size, void* d_ws, size_t ws_size,
                              hipStream_t stream) {
  const float* x         = (const float*)d_in[0];
  const float* cosb      = (const float*)d_in[1];
  const float* sinb      = (const float*)d_in[2];
  const float* Wq_nope   = (const float*)d_in[3];
  const float* Wq_rope   = (const float*)d_in[4];
  const float* g_qnope   = (const float*)d_in[5];
  const float* g_qrope   = (const float*)d_in[6];
  const float* W_kv_down = (const float*)d_in[7];
  const float* g_ckv     = (const float*)d_in[8];
  const float* W_k_nope  = (const float*)d_in[9];
  const float* W_k_rope  = (const float*)d_in[10];
  const float* W_v       = (const float*)d_in[11];
  const float* W_o       = (const float*)d_in[12];
  float* out = (float*)d_out;

  const int S = 2048;
  float* ws = (float*)d_ws;
  // fp32 region
  float* q_f   = ws;                 // 4,194,304 f (later reused as aob bf16)
  float* kbuf  = ws + 4194304;       // 1,048,576
  // vbuf = kbuf + 1,048,576 (mode-2 epilogue writes it via kbuf base)
  float* vbuf  = ws + 5242880;       // 1,048,576
  float* ckv_f = ws + 6291456;       // 1,048,576
  // bf16 region
  __hip_bfloat16* bb   = (__hip_bfloat16*)(ws + 7340032);
  __hip_bfloat16* xb   = bb;              // 4,194,304  (reused for Wob)
  __hip_bfloat16* Wqb  = bb + 4194304;    // 4,194,304  (reused for qb)
  __hip_bfloat16* Wkdb = bb + 8388608;    // 1,048,576  (reused for ckvb)
  __hip_bfloat16* Wkvb = bb + 9437184;    //   524,288
  __hip_bfloat16* kb   = bb + 9961472;    // 1,048,576
  __hip_bfloat16* vt   = bb + 11010048;   // 1,048,576
  __hip_bfloat16* Wob  = xb;
  __hip_bfloat16* qb   = Wqb;
  __hip_bfloat16* ckvb = Wkdb;
  __hip_bfloat16* aob  = (__hip_bfloat16*)q_f;

  dim3 blk(TPB);

  // input converts
  cvt_f2b<<<4096, blk, 0, stream>>>(x, xb, 4194304);
  cvt_f2b<<<2048, blk, 0, stream>>>(Wq_nope, Wqb, 2097152);
  cvt_f2b<<<2048, blk, 0, stream>>>(Wq_rope, Wqb + 2097152, 2097152);
  cvt_f2b<<<1024, blk, 0, stream>>>(W_kv_down, Wkdb, 1048576);
  cvt_f2b<<<128,  blk, 0, stream>>>(W_k_nope, Wkvb, 131072);
  cvt_f2b<<<128,  blk, 0, stream>>>(W_k_rope, Wkvb + 131072, 131072);
  cvt_f2b<<<256,  blk, 0, stream>>>(W_v, Wkvb + 262144, 262144);

  // q & ckv projections (K=2048)
  gemm_mfma<<<dim3(16, 16), blk, 0, stream>>>(xb, Wqb, q_f, 2048, 2048, 2048, 0, 1);
  gemm_mfma<<<dim3(4, 16),  blk, 0, stream>>>(xb, Wkdb, ckv_f, 2048, 512, 2048, 512, 0);
  // xb dead -> convert W_o into its slot
  cvt_f2b<<<4096, blk, 0, stream>>>(W_o, Wob, 4194304);

  // norms + rope (fp32)
  rmsrope64<<<dim3((S * 16) / 4), blk, 0, stream>>>(q_f, g_qnope, nullptr, nullptr,
                                                    S * 16, 16, 2048, 128, 0, 1, 0);
  rmsrope64<<<dim3((S * 16) / 4), blk, 0, stream>>>(q_f, g_qrope, cosb, sinb,
                                                    S * 16, 16, 2048, 128, 64, 1, 1);
  rms512<<<dim3(S / 4), blk, 0, stream>>>(ckv_f, g_ckv, S);

  cvt_f2b<<<4096, blk, 0, stream>>>(q_f, qb, 4194304);
  cvt_f2b<<<1024, blk, 0, stream>>>(ckv_f, ckvb, 1048576);

  // k/v projections (K=512), scatter into kbuf/vbuf
  gemm_mfma<<<dim3(8, 16), blk, 0, stream>>>(ckvb, Wkvb, kbuf, 2048, 1024, 512, 0, 2);
  rmsrope64<<<dim3((S * 4) / 4), blk, 0, stream>>>(kbuf, nullptr, cosb, sinb,
                                                   S * 4, 4, 512, 128, 64, 0, 1);
  cvt_f2b<<<1024, blk, 0, stream>>>(kbuf, kb, 1048576);
  cvt_transpose_v<<<dim3(2, 32, 4), blk, 0, stream>>>(vbuf, vt);

  // attention
  attn_mfma<<<dim3(16, 32), blk, 0, stream>>>(qb, kb, vt, aob);

  // output projection
  gemm_mfma<<<dim3(16, 16), blk, 0, stream>>>(aob, Wob, out, 2048, 2048, 2048, 2048, 0);
}

// Round 3
// 286.249 us; speedup vs baseline: 4.7272x; 1.3955x over previous
//
#include <hip/hip_runtime.h>
#include <hip/hip_bf16.h>
#include <math.h>

#define TPB 256

typedef __attribute__((ext_vector_type(8))) short bf16x8;
typedef __attribute__((ext_vector_type(4))) float f32x4;

__device__ __forceinline__ short f2bs(float x) {
  __hip_bfloat16 h = __float2bfloat16(x);
  return *reinterpret_cast<short*>(&h);
}

__device__ __forceinline__ void gll16(const void* g, void* l) {
  __builtin_amdgcn_global_load_lds(
      (const __attribute__((address_space(1))) unsigned int*)g,
      (__attribute__((address_space(3))) unsigned int*)l, 16, 0, 0);
}

// ---------------------------------------------------------------------------
// fp32 -> bf16 flat convert (n multiple of 1024*... grid covers exactly)
// ---------------------------------------------------------------------------
__global__ __launch_bounds__(TPB) void cvt_f2b(
    const float* __restrict__ s, short* __restrict__ d, int n)
{
  int i = (blockIdx.x * TPB + threadIdx.x) << 2;
  if (i >= n) return;
  const float4 v = *(const float4*)(s + i);
  short4 o;
  o.x = f2bs(v.x); o.y = f2bs(v.y); o.z = f2bs(v.z); o.w = f2bs(v.w);
  *(short4*)(d + i) = o;
}

// ---------------------------------------------------------------------------
// All weight tensors -> bf16 in one launch. Segment sizes in 1024-elem blocks:
// Wq_nope 2048 | Wq_rope 2048 | W_kv_down 1024 | W_k_nope 128 | W_k_rope 128
// | W_v 256 | W_o 4096   => 9728 blocks
// ---------------------------------------------------------------------------
__global__ __launch_bounds__(TPB) void cvt_weights(
    const float* __restrict__ w0, const float* __restrict__ w1,
    const float* __restrict__ w2, const float* __restrict__ w3,
    const float* __restrict__ w4, const float* __restrict__ w5,
    const float* __restrict__ w6,
    short* __restrict__ Wcat, short* __restrict__ Wkvb, short* __restrict__ Wob)
{
  int b = blockIdx.x;
  const float* src; short* dst; int base;
  if (b < 2048)      { src = w0; dst = Wcat;           base = b; }
  else if (b < 4096) { src = w1; dst = Wcat + 2097152; base = b - 2048; }
  else if (b < 5120) { src = w2; dst = Wcat + 4194304; base = b - 4096; }
  else if (b < 5248) { src = w3; dst = Wkvb;           base = b - 5120; }
  else if (b < 5376) { src = w4; dst = Wkvb + 131072;  base = b - 5248; }
  else if (b < 5632) { src = w5; dst = Wkvb + 262144;  base = b - 5376; }
  else               { src = w6; dst = Wob;            base = b - 5632; }
  int i = base * 1024 + threadIdx.x * 4;
  float4 v = *(const float4*)(src + i);
  short4 o;
  o.x = f2bs(v.x); o.y = f2bs(v.y); o.z = f2bs(v.z); o.w = f2bs(v.w);
  *(short4*)(dst + i) = o;
}

// ---------------------------------------------------------------------------
// RMS over 512-wide rows, fp32 in -> bf16 out (one wave per row)
// ---------------------------------------------------------------------------
__global__ __launch_bounds__(TPB) void rms512b(
    const float* __restrict__ src, short* __restrict__ dst,
    const float* __restrict__ g, int nrows)
{
  int row = blockIdx.x * (TPB / 64) + (threadIdx.x >> 6);
  int l = threadIdx.x & 63;
  if (row >= nrows) return;
  const float* p = src + (size_t)row * 512;
  float x[8];
  float ss = 0.f;
#pragma unroll
  for (int i = 0; i < 8; ++i) { x[i] = p[i * 64 + l]; ss += x[i] * x[i]; }
#pragma unroll
  for (int msk = 1; msk < 64; msk <<= 1) ss += __shfl_xor(ss, msk);
  float r = rsqrtf(ss * (1.0f / 512.0f) + 1e-6f);
#pragma unroll
  for (int i = 0; i < 8; ++i)
    dst[(size_t)row * 512 + i * 64 + l] = f2bs(x[i] * r * g[i * 64 + l]);
}

// ---------------------------------------------------------------------------
// Fused MFMA GEMM: acc = A[M,K](bf16) @ W[N,K](bf16)^T, 128x128 tile, BK=64,
// double-buffered global_load_lds staging, ONE barrier per K-step.
// MODE 0: C fp32 [m*ldc + gn]                                  (W_o GEMM)
// MODE 1: qkv projection: gn<1024 RMS->qb nope | 1024..2047 RMS+rope->qb rope
//         | >=2048 raw fp32 ckv_f                              (x GEMM)
// MODE 2: kv: gn<256 ->kb nope | 256..511 rope->kb | >=512 ->vt transposed
// ---------------------------------------------------------------------------
template <int MODE>
__global__ __launch_bounds__(TPB) void gemm_fused(
    const short* __restrict__ A, const short* __restrict__ W,
    float* __restrict__ Cf, short* __restrict__ qk_out, short* __restrict__ vt,
    float* __restrict__ ckv_f,
    const float* __restrict__ cosb, const float* __restrict__ sinb,
    const float* __restrict__ g_qnope, const float* __restrict__ g_qrope,
    int M, int N, int K, int ldc)
{
  __shared__ short As[2][128 * 64];
  __shared__ short Bs[2][128 * 64];
  const int t = threadIdx.x;
  const int lane = t & 63, wave = t >> 6;
  const int wr = wave >> 1, wc = wave & 1;
  const int li = lane & 15, lh = lane >> 4;
  const int bm = blockIdx.y * 128, bn = blockIdx.x * 128;

  f32x4 acc[4][4];
#pragma unroll
  for (int m = 0; m < 4; ++m)
#pragma unroll
    for (int n = 0; n < 4; ++n) acc[m][n] = (f32x4){0.f, 0.f, 0.f, 0.f};

#define GSTAGE(buf, k0)                                                        \
  {                                                                            \
    _Pragma("unroll") for (int i = 0; i < 4; ++i) {                            \
      int id = i * 256 + t;                                                    \
      int r = id >> 3, cl = id & 7;                                            \
      gll16(A + (size_t)(bm + r) * K + (k0) + ((cl ^ (r & 7)) << 3),           \
            &As[buf][id * 8]);                                                 \
    }                                                                          \
    _Pragma("unroll") for (int i = 0; i < 4; ++i) {                            \
      int id = i * 256 + t;                                                    \
      int r = id >> 3, cl = id & 7;                                            \
      gll16(W + (size_t)(bn + r) * K + (k0) + ((cl ^ (r & 7)) << 3),           \
            &Bs[buf][id * 8]);                                                 \
    }                                                                          \
  }

  GSTAGE(0, 0);
  int cur = 0;
  for (int k0 = 0; k0 < K; k0 += 64) {
    __syncthreads();  // drains stage(cur); prev iter's LDS reads already consumed
    if (k0 + 64 < K) GSTAGE(cur ^ 1, k0 + 64);
    bf16x8 af[2][4], bf[2][4];
#pragma unroll
    for (int m = 0; m < 4; ++m) {
      int r = wr * 64 + m * 16 + li;
#pragma unroll
      for (int kd = 0; kd < 2; ++kd)
        af[kd][m] = *(const bf16x8*)&As[cur][r * 64 + (((kd * 4 + lh) ^ (r & 7)) << 3)];
    }
#pragma unroll
    for (int n = 0; n < 4; ++n) {
      int r = wc * 64 + n * 16 + li;
#pragma unroll
      for (int kd = 0; kd < 2; ++kd)
        bf[kd][n] = *(const bf16x8*)&Bs[cur][r * 64 + (((kd * 4 + lh) ^ (r & 7)) << 3)];
    }
#pragma unroll
    for (int kd = 0; kd < 2; ++kd)
#pragma unroll
      for (int m = 0; m < 4; ++m)
#pragma unroll
        for (int n = 0; n < 4; ++n)
          acc[m][n] = __builtin_amdgcn_mfma_f32_16x16x32_bf16(af[kd][m], bf[kd][n],
                                                              acc[m][n], 0, 0, 0);
    cur ^= 1;
  }
#undef GSTAGE

  const int colbase = bn + wc * 64;  // wave-uniform, 64-aligned

  if (MODE == 0) {
#pragma unroll
    for (int m = 0; m < 4; ++m) {
      int gm = bm + wr * 64 + m * 16 + lh * 4;
#pragma unroll
      for (int n = 0; n < 4; ++n) {
        int gn = colbase + n * 16 + li;
#pragma unroll
        for (int j = 0; j < 4; ++j)
          Cf[(size_t)(gm + j) * ldc + gn] = acc[m][n][j];
      }
    }
  }

  if (MODE == 1) {
    if (colbase < 2048) {
      const bool isrope = colbase >= 1024;
      const int head = (colbase & 1023) >> 6;
      const float* g = isrope ? g_qrope : g_qnope;
      float gv[4];
#pragma unroll
      for (int nf = 0; nf < 4; ++nf) gv[nf] = g[nf * 16 + li];
#pragma unroll
      for (int m = 0; m < 4; ++m) {
#pragma unroll
        for (int j = 0; j < 4; ++j) {
          int s = bm + wr * 64 + m * 16 + lh * 4 + j;
          float sum = acc[m][0][j] * acc[m][0][j] + acc[m][1][j] * acc[m][1][j] +
                      acc[m][2][j] * acc[m][2][j] + acc[m][3][j] * acc[m][3][j];
          sum += __shfl_xor(sum, 1); sum += __shfl_xor(sum, 2);
          sum += __shfl_xor(sum, 4); sum += __shfl_xor(sum, 8);
          float r = rsqrtf(sum * (1.0f / 64.0f) + 1e-6f);
          float y[4];
#pragma unroll
          for (int nf = 0; nf < 4; ++nf) y[nf] = acc[m][nf][j] * r * gv[nf];
          if (isrope) {
            float yr[4];
#pragma unroll
            for (int nf = 0; nf < 4; ++nf) {
              int c = nf * 16 + li;
              float cs = cosb[s * 64 + c], sn = sinb[s * 64 + c];
              float par = (nf < 2) ? -y[nf + 2] : y[nf - 2];
              yr[nf] = y[nf] * cs + par * sn;
            }
#pragma unroll
            for (int nf = 0; nf < 4; ++nf) y[nf] = yr[nf];
          }
#pragma unroll
          for (int nf = 0; nf < 4; ++nf)
            qk_out[(size_t)s * 2048 + head * 128 + (isrope ? 64 : 0) + nf * 16 + li] =
                f2bs(y[nf]);
        }
      }
    } else {
      const int c0 = colbase - 2048;
#pragma unroll
      for (int m = 0; m < 4; ++m) {
        int gm = bm + wr * 64 + m * 16 + lh * 4;
#pragma unroll
        for (int n = 0; n < 4; ++n) {
          int c = c0 + n * 16 + li;
#pragma unroll
          for (int j = 0; j < 4; ++j)
            ckv_f[(size_t)(gm + j) * 512 + c] = acc[m][n][j];
        }
      }
    }
  }

  if (MODE == 2) {
    if (colbase < 512) {
      const bool isrope = colbase >= 256;
      const int kvh = (colbase & 255) >> 6;
#pragma unroll
      for (int m = 0; m < 4; ++m) {
#pragma unroll
        for (int j = 0; j < 4; ++j) {
          int s = bm + wr * 64 + m * 16 + lh * 4 + j;
          float y[4];
#pragma unroll
          for (int nf = 0; nf < 4; ++nf) y[nf] = acc[m][nf][j];
          if (isrope) {
            float yr[4];
#pragma unroll
            for (int nf = 0; nf < 4; ++nf) {
              int c = nf * 16 + li;
              float cs = cosb[s * 64 + c], sn = sinb[s * 64 + c];
              float par = (nf < 2) ? -y[nf + 2] : y[nf - 2];
              yr[nf] = y[nf] * cs + par * sn;
            }
#pragma unroll
            for (int nf = 0; nf < 4; ++nf) y[nf] = yr[nf];
          }
#pragma unroll
          for (int nf = 0; nf < 4; ++nf)
            qk_out[(size_t)s * 512 + kvh * 128 + (isrope ? 64 : 0) + nf * 16 + li] =
                f2bs(y[nf]);
        }
      }
    } else {
#pragma unroll
      for (int m = 0; m < 4; ++m) {
        int s0 = bm + wr * 64 + m * 16 + lh * 4;
#pragma unroll
        for (int nf = 0; nf < 4; ++nf) {
          int d = colbase - 512 + nf * 16 + li;
          int kvh = d >> 7, dd = d & 127;
          short4 pk;
          pk.x = f2bs(acc[m][nf][0]); pk.y = f2bs(acc[m][nf][1]);
          pk.z = f2bs(acc[m][nf][2]); pk.w = f2bs(acc[m][nf][3]);
          *(short4*)&vt[(size_t)kvh * 262144 + (size_t)dd * 2048 + s0] = pk;
        }
      }
    }
  }
}

// ---------------------------------------------------------------------------
// MFMA flash attention, causal, double-buffered K/V staging, 1 barrier/tile.
// Block = 4 waves, BQ=64 (16 q-rows/wave), BK=64, HD=128.
// qb [S][16*128], kb [S][4*128], vt [4][128][S], ob bf16 [S][16*128]
// ---------------------------------------------------------------------------
__global__ __launch_bounds__(TPB) void attn_mfma(
    const short* __restrict__ qb, const short* __restrict__ kb,
    const short* __restrict__ vt, short* __restrict__ ob)
{
  __shared__ short Ks[2][64 * 128];   // [kpos][d] swizzled
  __shared__ short Vs[2][128 * 64];   // [d][kpos] swizzled
  __shared__ short Ps[4][16 * 64];    // per-wave [q][kpos] swizzled
  const int h = blockIdx.x;
  const int qt = gridDim.y - 1 - blockIdx.y;  // longest blocks first
  const int kvh = h >> 2;
  const int t = threadIdx.x, lane = t & 63, wave = t >> 6;
  const int li = lane & 15, lh = lane >> 4;
  const int q0 = qt * 64, q0w = q0 + wave * 16;
  const float scale = 0.08838834764831845f;  // 1/sqrt(128)

  bf16x8 qf[4];
#pragma unroll
  for (int kd = 0; kd < 4; ++kd)
    qf[kd] = *(const bf16x8*)(qb + (size_t)(q0w + li) * 2048 + h * 128 + kd * 32 + lh * 8);

  f32x4 o[8];
#pragma unroll
  for (int n = 0; n < 8; ++n) o[n] = (f32x4){0.f, 0.f, 0.f, 0.f};
  float m_i[4] = {-1e30f, -1e30f, -1e30f, -1e30f};
  float l_i[4] = {0.f, 0.f, 0.f, 0.f};

#define ASTAGE(buf, kbase)                                                     \
  {                                                                            \
    _Pragma("unroll") for (int i = 0; i < 4; ++i) {                            \
      int c = t + i * 256;                                                     \
      int kpos = c >> 4, dcl = (c & 15) ^ (kpos & 7);                          \
      gll16(kb + (size_t)((kbase) + kpos) * 512 + kvh * 128 + dcl * 8,         \
            &Ks[buf][c * 8]);                                                  \
    }                                                                          \
    _Pragma("unroll") for (int i = 0; i < 4; ++i) {                            \
      int c = t + i * 256;                                                     \
      int d = c >> 3, kpl = (c & 7) ^ (d & 7);                                 \
      gll16(vt + (size_t)kvh * 262144 + (size_t)d * 2048 + (kbase) + kpl * 8,  \
            &Vs[buf][c * 8]);                                                  \
    }                                                                          \
  }

  short* pw = Ps[wave];
  const int nkt = qt + 1;
  ASTAGE(0, 0);
  int cur = 0;
  for (int kt = 0; kt < nkt; ++kt) {
    const int kbase = kt * 64;
    __syncthreads();  // drains stage(cur); all waves done reading buf cur^1
    if (kt + 1 < nkt) ASTAGE(cur ^ 1, kbase + 64);

    // ---- S = Q K^T ----
    f32x4 s[4];
#pragma unroll
    for (int n = 0; n < 4; ++n) s[n] = (f32x4){0.f, 0.f, 0.f, 0.f};
#pragma unroll
    for (int n = 0; n < 4; ++n) {
      int kpos = n * 16 + li;
#pragma unroll
      for (int kd = 0; kd < 4; ++kd) {
        int cph = (kd * 4 + lh) ^ (kpos & 7);
        bf16x8 kf = *(const bf16x8*)&Ks[cur][kpos * 128 + cph * 8];
        s[n] = __builtin_amdgcn_mfma_f32_16x16x32_bf16(qf[kd], kf, s[n], 0, 0, 0);
      }
    }
    // ---- scale + causal mask ----
    float sv[4][4];
    const bool diag = (kt == nkt - 1);
#pragma unroll
    for (int n = 0; n < 4; ++n)
#pragma unroll
      for (int j = 0; j < 4; ++j) {
        float val = s[n][j] * scale;
        if (diag) {
          int kg = kbase + n * 16 + li;
          int qg = q0w + lh * 4 + j;
          if (kg > qg) val = -1e30f;
        }
        sv[n][j] = val;
      }
    // ---- online softmax ----
    float c_[4];
#pragma unroll
    for (int j = 0; j < 4; ++j) {
      float rm = fmaxf(fmaxf(sv[0][j], sv[1][j]), fmaxf(sv[2][j], sv[3][j]));
      rm = fmaxf(rm, __shfl_xor(rm, 1));
      rm = fmaxf(rm, __shfl_xor(rm, 2));
      rm = fmaxf(rm, __shfl_xor(rm, 4));
      rm = fmaxf(rm, __shfl_xor(rm, 8));
      float mn = fmaxf(m_i[j], rm);
      c_[j] = __expf(m_i[j] - mn);
      m_i[j] = mn;
    }
#pragma unroll
    for (int n = 0; n < 4; ++n)
#pragma unroll
      for (int j = 0; j < 4; ++j) sv[n][j] = __expf(sv[n][j] - m_i[j]);
#pragma unroll
    for (int j = 0; j < 4; ++j) {
      float rs = sv[0][j] + sv[1][j] + sv[2][j] + sv[3][j];
      rs += __shfl_xor(rs, 1);
      rs += __shfl_xor(rs, 2);
      rs += __shfl_xor(rs, 4);
      rs += __shfl_xor(rs, 8);
      l_i[j] = l_i[j] * c_[j] + rs;
    }
    // ---- P -> LDS (bf16, swizzled; per-wave buffer) ----
#pragma unroll
    for (int n = 0; n < 4; ++n)
#pragma unroll
      for (int j = 0; j < 4; ++j) {
        int qq = lh * 4 + j, kp = n * 16 + li;
        pw[qq * 64 + (kp ^ ((qq & 7) << 3))] = f2bs(sv[n][j]);
      }
    // ---- rescale O while P writes land ----
#pragma unroll
    for (int n = 0; n < 8; ++n)
#pragma unroll
      for (int j = 0; j < 4; ++j) o[n][j] *= c_[j];
    // same-wave LDS write->read fence (rule #18)
    asm volatile("s_waitcnt lgkmcnt(0)" ::: "memory");
    __builtin_amdgcn_sched_barrier(0);
    // ---- O += P V ----
#pragma unroll
    for (int kk = 0; kk < 2; ++kk) {
      int kp0 = kk * 32 + lh * 8;
      bf16x8 pf = *(const bf16x8*)&pw[li * 64 + (kp0 ^ ((li & 7) << 3))];
#pragma unroll
      for (int n = 0; n < 8; ++n) {
        int d = n * 16 + li;
        bf16x8 vf = *(const bf16x8*)&Vs[cur][d * 64 + (kp0 ^ ((d & 7) << 3))];
        o[n] = __builtin_amdgcn_mfma_f32_16x16x32_bf16(pf, vf, o[n], 0, 0, 0);
      }
    }
    cur ^= 1;
  }
#undef ASTAGE
  float inv[4];
#pragma unroll
  for (int j = 0; j < 4; ++j) inv[j] = 1.0f / l_i[j];
#pragma unroll
  for (int n = 0; n < 8; ++n)
#pragma unroll
    for (int j = 0; j < 4; ++j)
      ob[(size_t)(q0w + lh * 4 + j) * 2048 + h * 128 + n * 16 + li] =
          f2bs(o[n][j] * inv[j]);
}

// ---------------------------------------------------------------------------
extern "C" void kernel_launch(void* const* d_in, const int* in_sizes, int n_in,
                              void* d_out, int out_size, void* d_ws, size_t ws_size,
                              hipStream_t stream) {
  const float* x         = (const float*)d_in[0];
  const float* cosb      = (const float*)d_in[1];
  const float* sinb      = (const float*)d_in[2];
  const float* Wq_nope   = (const float*)d_in[3];
  const float* Wq_rope   = (const float*)d_in[4];
  const float* g_qnope   = (const float*)d_in[5];
  const float* g_qrope   = (const float*)d_in[6];
  const float* W_kv_down = (const float*)d_in[7];
  const float* g_ckv     = (const float*)d_in[8];
  const float* W_k_nope  = (const float*)d_in[9];
  const float* W_k_rope  = (const float*)d_in[10];
  const float* W_v       = (const float*)d_in[11];
  const float* W_o       = (const float*)d_in[12];
  float* out = (float*)d_out;

  float* ws = (float*)d_ws;
  float* ckv_f = ws;                         // 1,048,576 floats
  short* sb   = (short*)(ws + 1048576);
  short* xb   = sb;                          // 4,194,304 (reused as aob)
  short* Wcat = sb + 4194304;                // 5,242,880  [2560][2048]
  short* Wkvb = Wcat + 5242880;              //   524,288  [1024][512]
  short* Wob  = Wkvb + 524288;               // 4,194,304
  short* qb   = Wob + 4194304;               // 4,194,304
  short* ckvb = qb + 4194304;                // 1,048,576
  short* kb   = ckvb + 1048576;              // 1,048,576
  short* vt   = kb + 1048576;                // 1,048,576
  short* aob  = xb;

  dim3 blk(TPB);

  cvt_f2b<<<4096, blk, 0, stream>>>(x, xb, 4194304);
  cvt_weights<<<9728, blk, 0, stream>>>(Wq_nope, Wq_rope, W_kv_down, W_k_nope,
                                        W_k_rope, W_v, W_o, Wcat, Wkvb, Wob);

  // x @ [Wq_nope; Wq_rope; W_kv_down]^T  (N=2560, K=2048) fused RMS/rope -> qb, ckv_f
  gemm_fused<1><<<dim3(20, 16), blk, 0, stream>>>(
      xb, Wcat, nullptr, qb, nullptr, ckv_f, cosb, sinb, g_qnope, g_qrope,
      2048, 2560, 2048, 0);

  rms512b<<<512, blk, 0, stream>>>(ckv_f, ckvb, g_ckv, 2048);

  // ckv @ [W_k_nope; W_k_rope; W_v]^T (N=1024, K=512) fused rope/transpose -> kb, vt
  gemm_fused<2><<<dim3(8, 16), blk, 0, stream>>>(
      ckvb, Wkvb, nullptr, kb, vt, nullptr, cosb, sinb, nullptr, nullptr,
      2048, 1024, 512, 0);

  attn_mfma<<<dim3(16, 32), blk, 0, stream>>>(qb, kb, vt, aob);

  // out = ao @ W_o^T (N=2048, K=2048)
  gemm_fused<0><<<dim3(16, 16), blk, 0, stream>>>(
      aob, Wob, out, nullptr, nullptr, nullptr, nullptr, nullptr, nullptr, nullptr,
      2048, 2048, 2048, 2048);
}